// Round 18
// baseline (158.771 us; speedup 1.0000x reference)
//
#include <hip/hip_runtime.h>
#include <hip/hip_bf16.h>

#define Bn 4
#define Ln 4096
#define Dn 1024
#define Hn 16
#define KSEL 41

typedef __attribute__((ext_vector_type(8))) _Float16 f16x8;
typedef __attribute__((ext_vector_type(4))) _Float16 f16x4;
typedef __attribute__((ext_vector_type(4))) float f32x4;

// ---------- f32 -> f16 bits (RNE via hardware cvt) ----------
__device__ __forceinline__ unsigned short f2h(float f) {
    union { _Float16 h; unsigned short u; } c;
    c.h = (_Float16)f;
    return c.u;
}

// ---------- async global->LDS, 16B per lane ----------
__device__ __forceinline__ void gl2lds16(const unsigned short* g, unsigned short* l) {
    __builtin_amdgcn_global_load_lds(
        (const __attribute__((address_space(1))) unsigned int*)(uintptr_t)g,
        (__attribute__((address_space(3))) unsigned int*)(uintptr_t)l,
        16, 0, 0);
}

// ================= prep kernel: Wc GEMM + bcvec =================
// blocks [0,256): Wc = Wo @ Wv (NN f16 GEMM, register double-buffered)
// blocks [256,320): bc = Wo @ bv + bo
__global__ __launch_bounds__(256) void prepA(const float* __restrict__ Wo,
                                             const float* __restrict__ Wv,
                                             const float* __restrict__ bv,
                                             const float* __restrict__ bo,
                                             unsigned short* __restrict__ Wcf,
                                             float* __restrict__ bc) {
    __shared__ __align__(16) float S[2048];   // 8 KB
    int bid = blockIdx.x;
    int tid = threadIdx.x;
    if (bid < 256) {
        unsigned short* sA = (unsigned short*)S;            // [64 n][32 j]
        unsigned short* sB = (unsigned short*)S + 64 * 32;  // [64 k][32 j] transposed
        int n0 = (bid >> 4) * 64, k0 = (bid & 15) * 64;
        const int wv = tid >> 6, lane = tid & 63;
        const int wr = wv >> 1, wc = wv & 1;
        const int lrow = lane & 15, lk = (lane >> 4) * 8;
        const int ar0 = tid >> 3,  ac0 = (tid & 7) * 4;
        const int ar1 = (tid + 256) >> 3, ac1 = ((tid + 256) & 7) * 4;
        const int jr0 = tid >> 4,  kc0 = (tid & 15) * 4;
        const int jr1 = (tid + 256) >> 4, kc1 = ((tid + 256) & 15) * 4;
        f32x4 acc[2][2];
        #pragma unroll
        for (int i = 0; i < 2; ++i)
            #pragma unroll
            for (int j = 0; j < 2; ++j) acc[i][j] = (f32x4){0.f, 0.f, 0.f, 0.f};
        float4 avA, avB, bvA, bvB;
        auto LOADW = [&](int j0) {
            avA = *(const float4*)&Wo[(size_t)(n0 + ar0) * 1024 + j0 + ac0];
            avB = *(const float4*)&Wo[(size_t)(n0 + ar1) * 1024 + j0 + ac1];
            bvA = *(const float4*)&Wv[(size_t)(j0 + jr0) * 1024 + k0 + kc0];
            bvB = *(const float4*)&Wv[(size_t)(j0 + jr1) * 1024 + k0 + kc1];
        };
        LOADW(0);
        #pragma unroll 1
        for (int it = 0; it < 32; ++it) {
            ushort4 h;
            h.x = f2h(avA.x); h.y = f2h(avA.y); h.z = f2h(avA.z); h.w = f2h(avA.w);
            *(ushort4*)&sA[ar0 * 32 + ac0] = h;
            h.x = f2h(avB.x); h.y = f2h(avB.y); h.z = f2h(avB.z); h.w = f2h(avB.w);
            *(ushort4*)&sA[ar1 * 32 + ac1] = h;
            sB[(kc0 + 0) * 32 + jr0] = f2h(bvA.x);
            sB[(kc0 + 1) * 32 + jr0] = f2h(bvA.y);
            sB[(kc0 + 2) * 32 + jr0] = f2h(bvA.z);
            sB[(kc0 + 3) * 32 + jr0] = f2h(bvA.w);
            sB[(kc1 + 0) * 32 + jr1] = f2h(bvB.x);
            sB[(kc1 + 1) * 32 + jr1] = f2h(bvB.y);
            sB[(kc1 + 2) * 32 + jr1] = f2h(bvB.z);
            sB[(kc1 + 3) * 32 + jr1] = f2h(bvB.w);
            __syncthreads();
            if (it + 1 < 32) LOADW((it + 1) * 32);
            f16x8 af[2], bf[2];
            #pragma unroll
            for (int i = 0; i < 2; ++i)
                af[i] = *(const f16x8*)&sA[(wr * 32 + i * 16 + lrow) * 32 + lk];
            #pragma unroll
            for (int j = 0; j < 2; ++j)
                bf[j] = *(const f16x8*)&sB[(wc * 32 + j * 16 + lrow) * 32 + lk];
            #pragma unroll
            for (int i = 0; i < 2; ++i)
                #pragma unroll
                for (int j = 0; j < 2; ++j)
                    acc[i][j] = __builtin_amdgcn_mfma_f32_16x16x32_f16(af[i], bf[j], acc[i][j], 0, 0, 0);
            __syncthreads();
        }
        #pragma unroll
        for (int i = 0; i < 2; ++i) {
            int r0 = n0 + wr * 32 + i * 16 + (lane >> 4) * 4;
            #pragma unroll
            for (int j = 0; j < 2; ++j) {
                int c = k0 + wc * 32 + j * 16 + (lane & 15);
                #pragma unroll
                for (int r = 0; r < 4; ++r)
                    Wcf[(size_t)(r0 + r) * 1024 + c] = f2h(acc[i][j][r]);
            }
        }
    } else {
        float* s_bv = S;   // 4 KB
        int b3 = bid - 256;
        for (int i = tid; i < 1024; i += 256) s_bv[i] = bv[i];
        __syncthreads();
        int wv2 = tid >> 6, lane = tid & 63;
        for (int rr = 0; rr < 4; ++rr) {
            int n = b3 * 16 + rr * 4 + wv2;
            float p = 0.f;
            for (int c = 0; c < 4; ++c) {
                float4 w4 = *(const float4*)(Wo + (size_t)n * 1024 + c * 256 + lane * 4);
                float4 s4 = *(const float4*)(s_bv + c * 256 + lane * 4);
                p += w4.x * s4.x + w4.y * s4.y + w4.z * s4.z + w4.w * s4.w;
            }
            for (int off = 1; off < 64; off <<= 1) p += __shfl_xor(p, off);
            if (lane == 0) bc[n] = p + bo[n];
        }
    }
}

// ================= main hetero kernel: big GEMM (O = v@Wc^T) ∥ colsum(q,k) =================
// blocks [0,1024): GEMM role — 128^2 tile m97 structure, A=v fp32 reg-staged+f16-converted,
//                  B=Wcf f16 via gl2lds, epilogue writes f16 O (no bias).
// blocks [1024,1536): colsum role — round-12/16 proven nt-load pattern (independent of GEMM).
// The GEMM is independent of the stats chain (gather commutes to the output side),
// so its MFMA work hides under colsum's ~2.8 TB/s DMA shadow (m114 pipe overlap).
__global__ __launch_bounds__(256) void mainwork(const float* __restrict__ v,
                                                const float* __restrict__ q,
                                                const float* __restrict__ k,
                                                const unsigned short* __restrict__ Wcf,
                                                unsigned short* __restrict__ Of,
                                                float* __restrict__ part) {
    __shared__ __align__(16) unsigned short sAB[8192];   // 16 KB
    int bid = blockIdx.x;
    int tid = threadIdx.x;

    if (bid < 1024) {
        // ---- GEMM role ----
        unsigned short* sA = sAB;          // [128][32] f16
        unsigned short* sB = sAB + 4096;   // [128][32] f16
        int swz = (bid & 7) * 128 + (bid >> 3);   // XCD swizzle, nwg=1024
        int by = swz >> 3, bx = swz & 7;          // 128 x 8 tiles

        const int wave = tid >> 6, lane = tid & 63;
        const int lrow = lane & 15, lk = (lane >> 4) * 8;
        const int wr = wave >> 1, wc = wave & 1;
        const int arow = tid >> 3, acol = (tid & 7) * 4;   // A-staging: 32 rows/round
        const int srow = lane >> 2, skq = (lane & 3) * 8;  // B gl2lds mapping

        f32x4 acc[4][4];
        #pragma unroll
        for (int i = 0; i < 4; ++i)
            #pragma unroll
            for (int j = 0; j < 4; ++j) acc[i][j] = (f32x4){0.f, 0.f, 0.f, 0.f};

        const float* Av = v + (size_t)(by * 128) * 1024;
        float4 p0, p1, p2, p3;
        auto LOADA = [&](int k0) {
            p0 = *(const float4*)&Av[(size_t)(0 * 32 + arow) * 1024 + k0 + acol];
            p1 = *(const float4*)&Av[(size_t)(1 * 32 + arow) * 1024 + k0 + acol];
            p2 = *(const float4*)&Av[(size_t)(2 * 32 + arow) * 1024 + k0 + acol];
            p3 = *(const float4*)&Av[(size_t)(3 * 32 + arow) * 1024 + k0 + acol];
        };
        LOADA(0);
        #pragma unroll 1
        for (int it = 0; it < 32; ++it) {
            int k0 = it * 32;
            ushort4 h;
            h.x = f2h(p0.x); h.y = f2h(p0.y); h.z = f2h(p0.z); h.w = f2h(p0.w);
            *(ushort4*)&sA[(0 * 32 + arow) * 32 + acol] = h;
            h.x = f2h(p1.x); h.y = f2h(p1.y); h.z = f2h(p1.z); h.w = f2h(p1.w);
            *(ushort4*)&sA[(1 * 32 + arow) * 32 + acol] = h;
            h.x = f2h(p2.x); h.y = f2h(p2.y); h.z = f2h(p2.z); h.w = f2h(p2.w);
            *(ushort4*)&sA[(2 * 32 + arow) * 32 + acol] = h;
            h.x = f2h(p3.x); h.y = f2h(p3.y); h.z = f2h(p3.z); h.w = f2h(p3.w);
            *(ushort4*)&sA[(3 * 32 + arow) * 32 + acol] = h;
            #pragma unroll
            for (int j = 0; j < 2; ++j) {
                int chunk = j * 4 + wave;
                int row = chunk * 16 + srow;
                gl2lds16(Wcf + (size_t)(bx * 128 + row) * 1024 + k0 + skq, sB + chunk * 512);
            }
            __syncthreads();               // drains vmcnt (B landed) + sA writes visible
            if (it + 1 < 32) LOADA(k0 + 32);   // latency hides under MFMA + next barrier
            f16x8 bfrag[4];
            #pragma unroll
            for (int j = 0; j < 4; ++j)
                bfrag[j] = *(const f16x8*)&sB[(wc * 64 + j * 16 + lrow) * 32 + lk];
            #pragma unroll
            for (int i = 0; i < 4; ++i) {
                f16x8 afrag = *(const f16x8*)&sA[(wr * 64 + i * 16 + lrow) * 32 + lk];
                #pragma unroll
                for (int j = 0; j < 4; ++j)
                    acc[i][j] = __builtin_amdgcn_mfma_f32_16x16x32_f16(afrag, bfrag[j], acc[i][j], 0, 0, 0);
            }
            __syncthreads();
        }
        #pragma unroll
        for (int i = 0; i < 4; ++i) {
            int r0 = by * 128 + wr * 64 + i * 16 + (lane >> 4) * 4;
            #pragma unroll
            for (int j = 0; j < 4; ++j) {
                int c = bx * 128 + wc * 64 + j * 16 + (lane & 15);
                #pragma unroll
                for (int r = 0; r < 4; ++r)
                    Of[(size_t)(r0 + r) * 1024 + c] = f2h(acc[i][j][r]);
            }
        }
    } else {
        // ---- colsum role (proven nt-load pattern) ----
        int cid = bid - 1024;
        int cx = cid & 63, tb = cid >> 6;
        int tensor = tb >> 2, b = tb & 3;
        const f32x4* src = (const f32x4*)((tensor ? k : q) + (size_t)b * Ln * Dn) + tid;
        int t0 = cx * 64;
        f32x4 a0 = (f32x4){0.f, 0.f, 0.f, 0.f};
        f32x4 a1 = (f32x4){0.f, 0.f, 0.f, 0.f};
        #pragma unroll 1
        for (int g = 0; g < 8; ++g) {
            const f32x4* p = src + (size_t)(t0 + g * 8) * 256;
            f32x4 v0 = __builtin_nontemporal_load(p + 0 * 256);
            f32x4 v1 = __builtin_nontemporal_load(p + 1 * 256);
            f32x4 v2 = __builtin_nontemporal_load(p + 2 * 256);
            f32x4 v3 = __builtin_nontemporal_load(p + 3 * 256);
            f32x4 v4 = __builtin_nontemporal_load(p + 4 * 256);
            f32x4 v5 = __builtin_nontemporal_load(p + 5 * 256);
            f32x4 v6 = __builtin_nontemporal_load(p + 6 * 256);
            f32x4 v7 = __builtin_nontemporal_load(p + 7 * 256);
            a0 += v0 + v2 + v4 + v6;
            a1 += v1 + v3 + v5 + v7;
        }
        f32x4 o = a0 + a1;
        ((f32x4*)part)[((size_t)tb * 64 + cx) * 256 + tid] = o;
    }
}

// grid (4, 8): reduce 64 chunks per (tb, d)
__global__ void colsum_fin(const float* __restrict__ part, float* __restrict__ sums) {
    int tb = blockIdx.y; int d = blockIdx.x * 256 + threadIdx.x;
    float s = 0.f;
    for (int i = 0; i < 64; ++i) s += part[((size_t)tb * 64 + i) * 1024 + d];
    sums[(size_t)tb * 1024 + d] = s;
}

// ---------------- SQ/SK = colsum @ W^T + L*bias ----------------
__global__ void proj_sums(const float* __restrict__ sums,
                          const float* __restrict__ Wq, const float* __restrict__ bq,
                          const float* __restrict__ Wk, const float* __restrict__ bk,
                          float* __restrict__ SQK) {
    int t = blockIdx.y;
    const float* W    = t ? Wk : Wq;
    const float* bias = t ? bk : bq;
    const float* sv   = sums + (size_t)t * 4 * 1024;
    __shared__ float s_sv[4 * 1024];
    for (int i = threadIdx.x; i < 4 * 1024; i += 256) s_sv[i] = sv[i];
    __syncthreads();
    int wave = threadIdx.x >> 6, lane = threadIdx.x & 63;
    for (int rr = 0; rr < 4; ++rr) {
        int j = blockIdx.x * 16 + rr * 4 + wave;
        float p[4] = {0.f, 0.f, 0.f, 0.f};
        for (int c = 0; c < 4; ++c) {
            float4 wv = *(const float4*)(W + (size_t)j * 1024 + c * 256 + lane * 4);
            #pragma unroll
            for (int b = 0; b < 4; ++b) {
                float4 s = *(const float4*)(s_sv + b * 1024 + c * 256 + lane * 4);
                p[b] += wv.x * s.x + wv.y * s.y + wv.z * s.z + wv.w * s.w;
            }
        }
        #pragma unroll
        for (int b = 0; b < 4; ++b)
            for (int off = 1; off < 64; off <<= 1) p[b] += __shfl_xor(p[b], off);
        if (lane == 0) {
            float bb = bias[j] * (float)Ln;
            #pragma unroll
            for (int b = 0; b < 4; ++b) SQK[((size_t)t * 4 + b) * 1024 + j] = p[b] + bb;
        }
    }
}

// ---------------- fused mean_value + top-41 + softmax + dense tap table ----------------
__global__ void stats_topk(const float* __restrict__ SQK, int* __restrict__ dly,
                           float* __restrict__ gp) {
    __shared__ float s_mv[4][64];
    __shared__ float mab[64];
    __shared__ float selv[4][KSEL];
    __shared__ int   s_dly[KSEL];
    int tid = threadIdx.x; int b = tid >> 6, c = tid & 63;
    const float* SQ = SQK; const float* SK = SQK + 4 * 1024;
    float s = 0.f;
    for (int h = 0; h < Hn; ++h)
        s += SQ[(size_t)b * 1024 + h * 64 + c] * SK[(size_t)b * 1024 + h * 64 + c];
    s_mv[b][c] = s * (1.0f / ((float)Hn * (float)Ln));
    __syncthreads();
    if (tid < 64) mab[c] = (s_mv[0][c] + s_mv[1][c] + s_mv[2][c] + s_mv[3][c]) * 0.25f;
    __syncthreads();
    if (tid < 64) {
        float my = mab[c];
        int rank = 0;
        for (int j = 0; j < 64; ++j) {
            float vj = mab[j];
            rank += (vj > my) || (vj == my && j < c);
        }
        if (rank < KSEL) {
            s_dly[rank] = c;
            dly[rank] = c;
            selv[0][rank] = s_mv[0][c]; selv[1][rank] = s_mv[1][c];
            selv[2][rank] = s_mv[2][c]; selv[3][rank] = s_mv[3][c];
        }
    }
    __syncthreads();
    if (tid < 256) gp[tid] = 0.f;
    __syncthreads();
    if (tid < 4) {
        float mx = -1e30f;
        for (int i = 0; i < KSEL; ++i) mx = fmaxf(mx, selv[tid][i]);
        float ss = 0.f;
        for (int i = 0; i < KSEL; ++i) ss += expf(selv[tid][i] - mx);
        float inv = 1.0f / ss;
        for (int i = 0; i < KSEL; ++i)
            gp[tid * 64 + s_dly[i]] = expf(selv[tid][i] - mx) * inv;
    }
}

// ---------------- final gather on f16 O: out = FIR(O) + bc ----------------
#define FT 128
#define FC 64
#define FW 64
__global__ __launch_bounds__(256) void gather_o(const unsigned short* __restrict__ Of,
                                                const float* __restrict__ gp,
                                                const float* __restrict__ bc,
                                                float* __restrict__ out) {
    __shared__ unsigned short S[(FT + FW) * FC];   // 192 rows x 64 f16 = 24 KB
    int b = blockIdx.z, c0 = blockIdx.y * FC, t0 = blockIdx.x * FT;
    const unsigned short* Ob = Of + (size_t)b * Ln * Dn;
    #pragma unroll
    for (int it = 0; it < 6; ++it) {
        int idx = it * 256 + threadIdx.x;    // 16B slot: 8 f16; 8 slots/row
        int r = idx >> 3, cc = idx & 7;
        int gr = (t0 + r) & (Ln - 1);
        gl2lds16(Ob + (size_t)gr * 1024 + c0 + cc * 8, S + idx * 8);
    }
    __syncthreads();
    int c4 = threadIdx.x & 15, rg = threadIdx.x >> 4;   // 16 row-groups of 8 t
    const int base = rg * 8;
    float4 acc[8];
    #pragma unroll
    for (int i = 0; i < 8; ++i) acc[i] = make_float4(0.f, 0.f, 0.f, 0.f);
    #pragma unroll
    for (int tc = 0; tc < 2; ++tc) {
        float gc[32];
        #pragma unroll
        for (int j = 0; j < 8; ++j) {
            float4 gv = ((const float4*)(gp + b * 64 + tc * 32))[j];
            gc[j * 4 + 0] = gv.x; gc[j * 4 + 1] = gv.y;
            gc[j * 4 + 2] = gv.z; gc[j * 4 + 3] = gv.w;
        }
        #pragma unroll
        for (int w = 0; w < 39; ++w) {
            f16x4 hv = *(const f16x4*)&S[(base + tc * 32 + w) * FC + c4 * 4];
            float x0 = (float)hv[0], x1 = (float)hv[1], x2 = (float)hv[2], x3 = (float)hv[3];
            #pragma unroll
            for (int i = 0; i < 8; ++i) {
                int j = w - i;
                if (j >= 0 && j < 32) {
                    float wt = gc[j];
                    acc[i].x += wt * x0; acc[i].y += wt * x1;
                    acc[i].z += wt * x2; acc[i].w += wt * x3;
                }
            }
        }
    }
    float4 bias = *(const float4*)&bc[c0 + c4 * 4];
    #pragma unroll
    for (int i = 0; i < 8; ++i) {
        float4 o;
        o.x = acc[i].x + bias.x; o.y = acc[i].y + bias.y;
        o.z = acc[i].z + bias.z; o.w = acc[i].w + bias.w;
        *(float4*)&out[((size_t)b * Ln + t0 + base + i) * Dn + c0 + c4 * 4] = o;
    }
}

extern "C" void kernel_launch(void* const* d_in, const int* in_sizes, int n_in,
                              void* d_out, int out_size, void* d_ws, size_t ws_size,
                              hipStream_t stream) {
    const float* q  = (const float*)d_in[0];
    const float* k  = (const float*)d_in[1];
    const float* v  = (const float*)d_in[2];
    const float* Wq = (const float*)d_in[3];
    const float* bq = (const float*)d_in[4];
    const float* Wk = (const float*)d_in[5];
    const float* bk = (const float*)d_in[6];
    const float* Wv = (const float*)d_in[7];
    const float* bv = (const float*)d_in[8];
    const float* Wo = (const float*)d_in[9];
    const float* bo = (const float*)d_in[10];
    float* out = (float*)d_out;
    float* ws  = (float*)d_ws;

    unsigned short* Of  = (unsigned short*)ws;          // 16777216 ushort (32 MB)
    unsigned short* Wcf = Of + 16777216;                // 1048576
    float* part = (float*)(Wcf + 1048576);              // 524288 floats (2 MB)
    float* sums = part + 524288;                        // 8192
    float* SQK  = sums + 8192;                          // 8192
    float* gp   = SQK + 8192;                           // 256 (4 x 64 dense taps)
    float* bc   = gp + 256;                             // 1024
    int*   dly  = (int*)(bc + 1024);                    // 64

    // prep: Wc = Wo@Wv (f16) + bc = Wo@bv + bo
    hipLaunchKernelGGL(prepA, dim3(320), dim3(256), 0, stream, Wo, Wv, bv, bo, Wcf, bc);

    // main: big GEMM O = v@Wc^T (f16 out) CONCURRENT with colsum(q,k)
    hipLaunchKernelGGL(mainwork, dim3(1536), dim3(256), 0, stream, v, q, k, Wcf, Of, part);

    // stats chain -> dense tap table gp
    hipLaunchKernelGGL(colsum_fin, dim3(4, 8), dim3(256), 0, stream, part, sums);
    hipLaunchKernelGGL(proj_sums, dim3(64, 2), dim3(256), 0, stream, sums, Wq, bq, Wk, bk, SQK);
    hipLaunchKernelGGL(stats_topk, dim3(1), dim3(256), 0, stream, SQK, dly, gp);

    // final: out = FIR_gather(O) + bc
    hipLaunchKernelGGL(gather_o, dim3(32, 16, 4), dim3(256), 0, stream, Of, gp, bc, out);
}

// Round 19
// 135.631 us; speedup vs baseline: 1.1706x; 1.1706x over previous
//
#include <hip/hip_runtime.h>
#include <hip/hip_bf16.h>

#define Bn 4
#define Ln 4096
#define Dn 1024
#define Hn 16
#define KSEL 41
#define NT8 16   // K / 64 for the 8-phase GEMM

typedef __attribute__((ext_vector_type(8))) _Float16 f16x8;
typedef __attribute__((ext_vector_type(4))) float f32x4;

// ---------- f32 -> f16 bits (RNE via hardware cvt) ----------
__device__ __forceinline__ unsigned short f2h(float f) {
    union { _Float16 h; unsigned short u; } c;
    c.h = (_Float16)f;
    return c.u;
}

// ---------- async global->LDS, 16B per lane ----------
__device__ __forceinline__ void gl2lds16(const unsigned short* g, unsigned short* l) {
    __builtin_amdgcn_global_load_lds(
        (const __attribute__((address_space(1))) unsigned int*)(uintptr_t)g,
        (__attribute__((address_space(3))) unsigned int*)(uintptr_t)l,
        16, 0, 0);
}
__device__ __forceinline__ void gl2lds16f(const float* g, float* l) {
    __builtin_amdgcn_global_load_lds(
        (const __attribute__((address_space(1))) unsigned int*)(uintptr_t)g,
        (__attribute__((address_space(3))) unsigned int*)(uintptr_t)l,
        16, 0, 0);
}

// ================= heterogeneous pre-work kernel (round-16 proven) =================
// blocks [0,512):   colsum of q,k (nt-load pattern; ceiling-bound ~2.8 TB/s —
//                   5 mechanically-distinct variants all converge here)
// blocks [512,768): Wc = Wo @ Wv  (NN f16 GEMM, register double-buffered)
// blocks [768,832): bc = Wo @ bv + bo
__global__ __launch_bounds__(256) void prework(const float* __restrict__ q,
                                               const float* __restrict__ k,
                                               const float* __restrict__ Wq_unused,
                                               const float* __restrict__ Wo,
                                               const float* __restrict__ Wv,
                                               const float* __restrict__ bv,
                                               const float* __restrict__ bo,
                                               float* __restrict__ part,
                                               unsigned short* __restrict__ Wcf,
                                               float* __restrict__ bc) {
    __shared__ __align__(16) unsigned short sAB[2][64 * 32];   // 8 KB
    int bid = blockIdx.x;
    int tid = threadIdx.x;

    if (bid < 512) {
        // ---- colsum role ----
        int cx = bid & 63, tb = bid >> 6;
        int tensor = tb >> 2, b = tb & 3;
        const f32x4* src = (const f32x4*)((tensor ? k : q) + (size_t)b * Ln * Dn) + tid;
        int t0 = cx * 64;
        f32x4 a0 = (f32x4){0.f, 0.f, 0.f, 0.f};
        f32x4 a1 = (f32x4){0.f, 0.f, 0.f, 0.f};
        #pragma unroll 1
        for (int g = 0; g < 8; ++g) {
            const f32x4* p = src + (size_t)(t0 + g * 8) * 256;
            f32x4 v0 = __builtin_nontemporal_load(p + 0 * 256);
            f32x4 v1 = __builtin_nontemporal_load(p + 1 * 256);
            f32x4 v2 = __builtin_nontemporal_load(p + 2 * 256);
            f32x4 v3 = __builtin_nontemporal_load(p + 3 * 256);
            f32x4 v4 = __builtin_nontemporal_load(p + 4 * 256);
            f32x4 v5 = __builtin_nontemporal_load(p + 5 * 256);
            f32x4 v6 = __builtin_nontemporal_load(p + 6 * 256);
            f32x4 v7 = __builtin_nontemporal_load(p + 7 * 256);
            a0 += v0 + v2 + v4 + v6;
            a1 += v1 + v3 + v5 + v7;
        }
        f32x4 o = a0 + a1;
        ((f32x4*)part)[((size_t)tb * 64 + cx) * 256 + tid] = o;
    } else if (bid < 768) {
        // ---- small NN GEMM role (register double-buffered) ----
        unsigned short* sA = sAB[0];
        unsigned short* sB = sAB[1];
        int b2 = bid - 512;
        int n0 = (b2 >> 4) * 64, k0 = (b2 & 15) * 64;
        const int wv = tid >> 6, lane = tid & 63;
        const int wr = wv >> 1, wc = wv & 1;
        const int lrow = lane & 15, lk = (lane >> 4) * 8;
        const int ar0 = tid >> 3,  ac0 = (tid & 7) * 4;
        const int ar1 = (tid + 256) >> 3, ac1 = ((tid + 256) & 7) * 4;
        const int jr0 = tid >> 4,  kc0 = (tid & 15) * 4;
        const int jr1 = (tid + 256) >> 4, kc1 = ((tid + 256) & 15) * 4;
        f32x4 acc[2][2];
        #pragma unroll
        for (int i = 0; i < 2; ++i)
            #pragma unroll
            for (int j = 0; j < 2; ++j) acc[i][j] = (f32x4){0.f, 0.f, 0.f, 0.f};

        float4 avA, avB, bvA, bvB;
        auto LOADW = [&](int j0) {
            avA = *(const float4*)&Wo[(size_t)(n0 + ar0) * 1024 + j0 + ac0];
            avB = *(const float4*)&Wo[(size_t)(n0 + ar1) * 1024 + j0 + ac1];
            bvA = *(const float4*)&Wv[(size_t)(j0 + jr0) * 1024 + k0 + kc0];
            bvB = *(const float4*)&Wv[(size_t)(j0 + jr1) * 1024 + k0 + kc1];
        };
        LOADW(0);
        #pragma unroll 1
        for (int it = 0; it < 32; ++it) {
            ushort4 h;
            h.x = f2h(avA.x); h.y = f2h(avA.y); h.z = f2h(avA.z); h.w = f2h(avA.w);
            *(ushort4*)&sA[ar0 * 32 + ac0] = h;
            h.x = f2h(avB.x); h.y = f2h(avB.y); h.z = f2h(avB.z); h.w = f2h(avB.w);
            *(ushort4*)&sA[ar1 * 32 + ac1] = h;
            sB[(kc0 + 0) * 32 + jr0] = f2h(bvA.x);
            sB[(kc0 + 1) * 32 + jr0] = f2h(bvA.y);
            sB[(kc0 + 2) * 32 + jr0] = f2h(bvA.z);
            sB[(kc0 + 3) * 32 + jr0] = f2h(bvA.w);
            sB[(kc1 + 0) * 32 + jr1] = f2h(bvB.x);
            sB[(kc1 + 1) * 32 + jr1] = f2h(bvB.y);
            sB[(kc1 + 2) * 32 + jr1] = f2h(bvB.z);
            sB[(kc1 + 3) * 32 + jr1] = f2h(bvB.w);
            __syncthreads();
            if (it + 1 < 32) LOADW((it + 1) * 32);
            f16x8 af[2], bf[2];
            #pragma unroll
            for (int i = 0; i < 2; ++i)
                af[i] = *(const f16x8*)&sA[(wr * 32 + i * 16 + lrow) * 32 + lk];
            #pragma unroll
            for (int j = 0; j < 2; ++j)
                bf[j] = *(const f16x8*)&sB[(wc * 32 + j * 16 + lrow) * 32 + lk];
            #pragma unroll
            for (int i = 0; i < 2; ++i)
                #pragma unroll
                for (int j = 0; j < 2; ++j)
                    acc[i][j] = __builtin_amdgcn_mfma_f32_16x16x32_f16(af[i], bf[j], acc[i][j], 0, 0, 0);
            __syncthreads();
        }
        #pragma unroll
        for (int i = 0; i < 2; ++i) {
            int r0 = n0 + wr * 32 + i * 16 + (lane >> 4) * 4;
            #pragma unroll
            for (int j = 0; j < 2; ++j) {
                int c = k0 + wc * 32 + j * 16 + (lane & 15);
                #pragma unroll
                for (int r = 0; r < 4; ++r)
                    Wcf[(size_t)(r0 + r) * 1024 + c] = f2h(acc[i][j][r]);
            }
        }
    } else {
        // ---- bcvec role ----
        float* s_bv = (float*)sAB;
        int b3 = bid - 768;
        for (int i = tid; i < 1024; i += 256) s_bv[i] = bv[i];
        __syncthreads();
        int wv2 = tid >> 6, lane = tid & 63;
        for (int rr = 0; rr < 4; ++rr) {
            int n = b3 * 16 + rr * 4 + wv2;
            float p = 0.f;
            for (int c = 0; c < 4; ++c) {
                float4 w4 = *(const float4*)(Wo + (size_t)n * 1024 + c * 256 + lane * 4);
                float4 s4 = *(const float4*)(s_bv + c * 256 + lane * 4);
                p += w4.x * s4.x + w4.y * s4.y + w4.z * s4.z + w4.w * s4.w;
            }
            for (int off = 1; off < 64; off <<= 1) p += __shfl_xor(p, off);
            if (lane == 0) bc[n] = p + bo[n];
        }
    }
}

// grid (4, 8): reduce 64 chunks per (tb, d)
__global__ void colsum_fin(const float* __restrict__ part, float* __restrict__ sums) {
    int tb = blockIdx.y; int d = blockIdx.x * 256 + threadIdx.x;
    float s = 0.f;
    for (int i = 0; i < 64; ++i) s += part[((size_t)tb * 64 + i) * 1024 + d];
    sums[(size_t)tb * 1024 + d] = s;
}

// ---------------- SQ/SK = colsum @ W^T + L*bias ----------------
__global__ void proj_sums(const float* __restrict__ sums,
                          const float* __restrict__ Wq, const float* __restrict__ bq,
                          const float* __restrict__ Wk, const float* __restrict__ bk,
                          float* __restrict__ SQK) {
    int t = blockIdx.y;
    const float* W    = t ? Wk : Wq;
    const float* bias = t ? bk : bq;
    const float* sv   = sums + (size_t)t * 4 * 1024;
    __shared__ float s_sv[4 * 1024];
    for (int i = threadIdx.x; i < 4 * 1024; i += 256) s_sv[i] = sv[i];
    __syncthreads();
    int wave = threadIdx.x >> 6, lane = threadIdx.x & 63;
    for (int rr = 0; rr < 4; ++rr) {
        int j = blockIdx.x * 16 + rr * 4 + wave;
        float p[4] = {0.f, 0.f, 0.f, 0.f};
        for (int c = 0; c < 4; ++c) {
            float4 wv = *(const float4*)(W + (size_t)j * 1024 + c * 256 + lane * 4);
            #pragma unroll
            for (int b = 0; b < 4; ++b) {
                float4 s = *(const float4*)(s_sv + b * 1024 + c * 256 + lane * 4);
                p[b] += wv.x * s.x + wv.y * s.y + wv.z * s.z + wv.w * s.w;
            }
        }
        #pragma unroll
        for (int b = 0; b < 4; ++b)
            for (int off = 1; off < 64; off <<= 1) p[b] += __shfl_xor(p[b], off);
        if (lane == 0) {
            float bb = bias[j] * (float)Ln;
            #pragma unroll
            for (int b = 0; b < 4; ++b) SQK[((size_t)t * 4 + b) * 1024 + j] = p[b] + bb;
        }
    }
}

// ---------------- fused mean_value + top-41 + softmax + dense tap table ----------------
__global__ void stats_topk(const float* __restrict__ SQK, int* __restrict__ dly,
                           float* __restrict__ gp) {
    __shared__ float s_mv[4][64];
    __shared__ float mab[64];
    __shared__ float selv[4][KSEL];
    __shared__ int   s_dly[KSEL];
    int tid = threadIdx.x; int b = tid >> 6, c = tid & 63;
    const float* SQ = SQK; const float* SK = SQK + 4 * 1024;
    float s = 0.f;
    for (int h = 0; h < Hn; ++h)
        s += SQ[(size_t)b * 1024 + h * 64 + c] * SK[(size_t)b * 1024 + h * 64 + c];
    s_mv[b][c] = s * (1.0f / ((float)Hn * (float)Ln));
    __syncthreads();
    if (tid < 64) mab[c] = (s_mv[0][c] + s_mv[1][c] + s_mv[2][c] + s_mv[3][c]) * 0.25f;
    __syncthreads();
    if (tid < 64) {
        float my = mab[c];
        int rank = 0;
        for (int j = 0; j < 64; ++j) {
            float vj = mab[j];
            rank += (vj > my) || (vj == my && j < c);
        }
        if (rank < KSEL) {
            s_dly[rank] = c;
            dly[rank] = c;
            selv[0][rank] = s_mv[0][c]; selv[1][rank] = s_mv[1][c];
            selv[2][rank] = s_mv[2][c]; selv[3][rank] = s_mv[3][c];
        }
    }
    __syncthreads();
    if (tid < 256) gp[tid] = 0.f;
    __syncthreads();
    if (tid < 4) {
        float mx = -1e30f;
        for (int i = 0; i < KSEL; ++i) mx = fmaxf(mx, selv[tid][i]);
        float ss = 0.f;
        for (int i = 0; i < KSEL; ++i) ss += expf(selv[tid][i] - mx);
        float inv = 1.0f / ss;
        for (int i = 0; i < KSEL; ++i)
            gp[tid * 64 + s_dly[i]] = expf(selv[tid][i] - mx) * inv;
    }
}

// ---------------- gather as dense 64-tap FIR, 2 chunks of 32 taps -> f16 ----------------
#define FT 128
#define FC 64
#define FW 64
__global__ __launch_bounds__(256) void gather_fir(const float* __restrict__ v,
                                                  const float* __restrict__ gp,
                                                  unsigned short* __restrict__ Vf) {
    __shared__ float S[(FT + FW) * FC];   // 192 rows x 64 ch = 48 KB
    int b = blockIdx.z, c0 = blockIdx.y * FC, t0 = blockIdx.x * FT;
    const float* Vb = v + (size_t)b * Ln * Dn;
    #pragma unroll
    for (int it = 0; it < 12; ++it) {
        int idx = it * 256 + threadIdx.x;           // 16B slot
        int r = idx >> 4, cc = idx & 15;
        int gr = (t0 + r) & (Ln - 1);
        gl2lds16f(Vb + (size_t)gr * Dn + c0 + cc * 4, S + idx * 4);
    }
    __syncthreads();
    int c4 = threadIdx.x & 15, rg = threadIdx.x >> 4;   // 16 row-groups of 8 t
    const int base = rg * 8;
    float4 acc[8];
    #pragma unroll
    for (int i = 0; i < 8; ++i) acc[i] = make_float4(0.f, 0.f, 0.f, 0.f);
    #pragma unroll
    for (int tc = 0; tc < 2; ++tc) {
        float gc[32];
        #pragma unroll
        for (int j = 0; j < 8; ++j) {
            float4 gv = ((const float4*)(gp + b * 64 + tc * 32))[j];
            gc[j * 4 + 0] = gv.x; gc[j * 4 + 1] = gv.y;
            gc[j * 4 + 2] = gv.z; gc[j * 4 + 3] = gv.w;
        }
        #pragma unroll
        for (int w = 0; w < 39; ++w) {                  // 32 taps + 8 rows - 1
            float4 x = *(const float4*)&S[(base + tc * 32 + w) * FC + c4 * 4];
            #pragma unroll
            for (int i = 0; i < 8; ++i) {
                int j = w - i;                          // compile-time
                if (j >= 0 && j < 32) {
                    float wt = gc[j];
                    acc[i].x += wt * x.x; acc[i].y += wt * x.y;
                    acc[i].z += wt * x.z; acc[i].w += wt * x.w;
                }
            }
        }
    }
    #pragma unroll
    for (int i = 0; i < 8; ++i) {
        size_t idx = ((size_t)b * Ln + t0 + base + i) * Dn + c0 + c4 * 4;
        ushort4 o;
        o.x = f2h(acc[i].x); o.y = f2h(acc[i].y);
        o.z = f2h(acc[i].z); o.w = f2h(acc[i].w);
        *(ushort4*)&Vf[idx] = o;
    }
}

// ---------------- 8-phase 256x256 f16 GEMM ----------------
__device__ __forceinline__ void mm16q(const f16x8* a, const f16x8* b, f32x4 (&acc)[2][4]) {
    #pragma unroll
    for (int i = 0; i < 2; ++i)
        #pragma unroll
        for (int j = 0; j < 4; ++j)
            #pragma unroll
            for (int s = 0; s < 2; ++s)
                acc[i][j] = __builtin_amdgcn_mfma_f32_16x16x32_f16(a[i * 2 + s], b[j * 2 + s],
                                                                   acc[i][j], 0, 0, 0);
}

__global__ __launch_bounds__(512, 2) void gemm8p(const unsigned short* __restrict__ A,
                                                 const unsigned short* __restrict__ Bt,
                                                 float* __restrict__ C,
                                                 const float* __restrict__ bias) {
    __shared__ unsigned short lds[65536];   // 128 KB
    int bid = blockIdx.x;                   // 256 blocks
    int swz = (bid & 7) * 32 + (bid >> 3);  // XCD swizzle, nwg=256 % 8 == 0
    int by = swz >> 2, bx = swz & 3;

    const int tid = threadIdx.x;
    const int wv = tid >> 6, lane = tid & 63;
    const int wr = wv >> 1, wc = wv & 1;    // wave 4x2 grid within a quadrant
    const int srow = lane >> 3, sslot = lane & 7;

    f32x4 acc[4][2][4];
    #pragma unroll
    for (int q = 0; q < 4; ++q)
        #pragma unroll
        for (int i = 0; i < 2; ++i)
            #pragma unroll
            for (int j = 0; j < 4; ++j) acc[q][i][j] = (f32x4){0.f, 0.f, 0.f, 0.f};

    auto STAGE = [&](int t, int op, int mh) {
        unsigned short* hb = lds + ((((t & 1) * 2 + op) * 2 + mh) << 13);
        const unsigned short* G = op ? Bt : A;
        int base_row = (op ? bx : by) * 256 + mh * 128;
        #pragma unroll
        for (int i = 0; i < 2; ++i) {
            int rl = i * 64 + wv * 8 + srow;
            int cs = sslot ^ (rl & 7);
            gl2lds16(G + (size_t)(base_row + rl) * 1024 + t * 64 + cs * 8,
                     hb + i * 4096 + wv * 512);
        }
    };
    auto LDA = [&](int t, int h, f16x8* a) {
        const unsigned short* hb = lds + ((((t & 1) * 2 + 0) * 2 + h) << 13);
        #pragma unroll
        for (int i = 0; i < 2; ++i) {
            int rl = wr * 32 + i * 16 + (lane & 15);
            #pragma unroll
            for (int s = 0; s < 2; ++s) {
                int cs = s * 4 + (lane >> 4);
                a[i * 2 + s] = *(const f16x8*)(hb + rl * 64 + ((cs ^ (rl & 7)) << 3));
            }
        }
    };
    auto LDB = [&](int t, int h, f16x8* b) {
        const unsigned short* hb = lds + ((((t & 1) * 2 + 1) * 2 + h) << 13);
        #pragma unroll
        for (int j = 0; j < 4; ++j) {
            int rl = wc * 64 + j * 16 + (lane & 15);
            #pragma unroll
            for (int s = 0; s < 2; ++s) {
                int cs = s * 4 + (lane >> 4);
                b[j * 2 + s] = *(const f16x8*)(hb + rl * 64 + ((cs ^ (rl & 7)) << 3));
            }
        }
    };

    STAGE(0, 0, 0); STAGE(0, 1, 0); STAGE(0, 0, 1); STAGE(0, 1, 1);
    STAGE(1, 0, 0); STAGE(1, 1, 0); STAGE(1, 0, 1);
    asm volatile("s_waitcnt vmcnt(6)" ::: "memory");
    __builtin_amdgcn_s_barrier();

    f16x8 a0[4], a1[4], b[8];
    for (int t = 0; t < NT8; ++t) {
        const bool p1 = (t + 1 < NT8), p2 = (t + 2 < NT8);
        LDA(t, 0, a0); LDB(t, 0, b);
        if (p1) STAGE(t + 1, 1, 1);
        __builtin_amdgcn_s_barrier();
        asm volatile("s_waitcnt lgkmcnt(0)" ::: "memory");
        __builtin_amdgcn_sched_barrier(0);
        __builtin_amdgcn_s_setprio(1);
        mm16q(a0, b, acc[0]);
        __builtin_amdgcn_s_setprio(0);
        __builtin_amdgcn_s_barrier();
        LDA(t, 1, a1);
        if (p2) STAGE(t + 2, 0, 0);
        __builtin_amdgcn_s_barrier();
        asm volatile("s_waitcnt lgkmcnt(0)" ::: "memory");
        __builtin_amdgcn_sched_barrier(0);
        __builtin_amdgcn_s_setprio(1);
        mm16q(a1, b, acc[2]);
        __builtin_amdgcn_s_setprio(0);
        __builtin_amdgcn_s_barrier();
        LDB(t, 1, b);
        if (p2) STAGE(t + 2, 1, 0);
        __builtin_amdgcn_s_barrier();
        asm volatile("s_waitcnt lgkmcnt(0)" ::: "memory");
        __builtin_amdgcn_sched_barrier(0);
        __builtin_amdgcn_s_setprio(1);
        mm16q(a0, b, acc[1]);
        __builtin_amdgcn_s_setprio(0);
        __builtin_amdgcn_s_barrier();
        if (p2) STAGE(t + 2, 0, 1);
        if (p2) { asm volatile("s_waitcnt vmcnt(6)" ::: "memory"); }
        else    { asm volatile("s_waitcnt vmcnt(0)" ::: "memory"); }
        __builtin_amdgcn_s_barrier();
        __builtin_amdgcn_s_setprio(1);
        mm16q(a1, b, acc[3]);
        __builtin_amdgcn_s_setprio(0);
        __builtin_amdgcn_s_barrier();
    }

    const int lr = (lane >> 4) << 2, lc = lane & 15;
    #pragma unroll
    for (int q = 0; q < 4; ++q) {
        int rbase = by * 256 + (q >> 1) * 128 + wr * 32 + lr;
        int cbase = bx * 256 + (q & 1) * 128 + wc * 64 + lc;
        #pragma unroll
        for (int j = 0; j < 4; ++j) {
            int c = cbase + j * 16;
            float bb = bias[c];
            #pragma unroll
            for (int i = 0; i < 2; ++i)
                #pragma unroll
                for (int r = 0; r < 4; ++r)
                    C[(size_t)(rbase + i * 16 + r) * 1024 + c] = acc[q][i][j][r] + bb;
        }
    }
}

extern "C" void kernel_launch(void* const* d_in, const int* in_sizes, int n_in,
                              void* d_out, int out_size, void* d_ws, size_t ws_size,
                              hipStream_t stream) {
    const float* q  = (const float*)d_in[0];
    const float* k  = (const float*)d_in[1];
    const float* v  = (const float*)d_in[2];
    const float* Wq = (const float*)d_in[3];
    const float* bq = (const float*)d_in[4];
    const float* Wk = (const float*)d_in[5];
    const float* bk = (const float*)d_in[6];
    const float* Wv = (const float*)d_in[7];
    const float* bv = (const float*)d_in[8];
    const float* Wo = (const float*)d_in[9];
    const float* bo = (const float*)d_in[10];
    float* out = (float*)d_out;
    float* ws  = (float*)d_ws;

    unsigned short* Vf  = (unsigned short*)ws;          // 16777216 ushort (32 MB)
    unsigned short* Wcf = Vf + 16777216;                // 1048576
    float* part = (float*)(Wcf + 1048576);              // 524288 floats (2 MB)
    float* sums = part + 524288;                        // 8192
    float* SQK  = sums + 8192;                          // 8192
    float* gp   = SQK + 8192;                           // 256 (4 x 64 dense taps)
    float* bc   = gp + 256;                             // 1024
    int*   dly  = (int*)(bc + 1024);                    // 64

    // hetero pre-work: colsum(q,k) + Wc small-GEMM (pipelined) + bcvec
    hipLaunchKernelGGL(prework, dim3(832), dim3(256), 0, stream,
                       q, k, Wq, Wo, Wv, bv, bo, part, Wcf, bc);

    // stats chain -> dense tap table gp
    hipLaunchKernelGGL(colsum_fin, dim3(4, 8), dim3(256), 0, stream, part, sums);
    hipLaunchKernelGGL(proj_sums, dim3(64, 2), dim3(256), 0, stream, sums, Wq, bq, Wk, bk, SQK);
    hipLaunchKernelGGL(stats_topk, dim3(1), dim3(256), 0, stream, SQK, dly, gp);

    // gather on v as dense 64-tap FIR (2x32-tap chunks, FT=128) -> f16
    hipLaunchKernelGGL(gather_fir, dim3(32, 16, 4), dim3(256), 0, stream, v, gp, Vf);

    // out = Vagg @ Wc^T + bc : 8-phase 256^2 pipeline, grid 64x4 = 256 blocks
    hipLaunchKernelGGL(gemm8p, dim3(256), dim3(512), 0, stream, Vf, Wcf, out, bc);
}